// Round 2
// baseline (1102.915 us; speedup 1.0000x reference)
//
#include <hip/hip_runtime.h>
#include <hip/hip_bf16.h>

typedef __bf16 bf16;
typedef bf16 v8bf __attribute__((ext_vector_type(8)));
typedef bf16 v4bf __attribute__((ext_vector_type(4)));
typedef short v4s __attribute__((ext_vector_type(4)));
typedef float v4f __attribute__((ext_vector_type(4)));

constexpr int Bc = 2, Sc = 2048, Dc = 1024, Hc = 16, HDc = 64;
constexpr int Mr = Bc * Sc;  // 4096 rows for projection GEMMs

__device__ inline v4f mfma16(v8bf a, v8bf b, v4f c) {
    return __builtin_amdgcn_mfma_f32_16x16x32_bf16(a, b, c, 0, 0, 0);
}

// K=16 MFMA: A-fragment = lane holds A[m=l&15][k=(l>>4)*4+j] -- matches swapped-QK
// score layout exactly, so P feeds PV straight from registers.
__device__ inline v4f mfma16x16(v4bf a, v4bf b, v4f c) {
#if __has_builtin(__builtin_amdgcn_mfma_f32_16x16x16bf16_1k)
    v4s as, bs;
    __builtin_memcpy(&as, &a, 8);
    __builtin_memcpy(&bs, &b, 8);
    return __builtin_amdgcn_mfma_f32_16x16x16bf16_1k(as, bs, c, 0, 0, 0);
#else
    asm volatile("s_nop 1\n\tv_mfma_f32_16x16x16_bf16 %0, %1, %2, %0"
                 : "+v"(c) : "v"(a), "v"(b));
    return c;
#endif
}

__device__ inline void gload_lds16(const void* g, void* l) {
    __builtin_amdgcn_global_load_lds((__attribute__((address_space(1))) void*)g,
                                     (__attribute__((address_space(3))) void*)l, 16, 0, 0);
}

// ---------- weight transpose+cvt: fp32 W[k][n] -> bf16 Wt[n][k], 4 matrices stacked ----------
__global__ void wtrans_kernel(const float* __restrict__ Wq, const float* __restrict__ Wk,
                              const float* __restrict__ Wv, const float* __restrict__ Wo,
                              bf16* __restrict__ out) {
    __shared__ float t[32][33];
    const float* W = (blockIdx.z == 0) ? Wq : (blockIdx.z == 1) ? Wk : (blockIdx.z == 2) ? Wv : Wo;
    bf16* Wt = out + (size_t)blockIdx.z * (Dc * Dc);
    int x0 = blockIdx.x * 32, y0 = blockIdx.y * 32;
    int tx = threadIdx.x, ty = threadIdx.y;
#pragma unroll
    for (int i = 0; i < 4; i++)
        t[ty + 8 * i][tx] = W[(size_t)(y0 + ty + 8 * i) * Dc + x0 + tx];
    __syncthreads();
#pragma unroll
    for (int i = 0; i < 4; i++)
        Wt[(size_t)(x0 + ty + 8 * i) * Dc + y0 + tx] = (bf16)t[tx][ty + 8 * i];
}

// ---------- fp32 -> bf16 convert (vectorized) ----------
__global__ void cvt_kernel(const float* __restrict__ in, bf16* __restrict__ out) {
    size_t i = ((size_t)blockIdx.x * blockDim.x + threadIdx.x) * 8;
    float4 f0 = *(const float4*)(in + i);
    float4 f1 = *(const float4*)(in + i + 4);
    v8bf v;
    v[0] = (bf16)f0.x; v[1] = (bf16)f0.y; v[2] = (bf16)f0.z; v[3] = (bf16)f0.w;
    v[4] = (bf16)f1.x; v[5] = (bf16)f1.y; v[6] = (bf16)f1.z; v[7] = (bf16)f1.w;
    *(v8bf*)(out + i) = v;
}

// ---------- V transpose (bf16): per b, [S][D] -> [D][S] ----------
__global__ void vtrans_kernel(const bf16* __restrict__ V, bf16* __restrict__ Vt) {
    __shared__ bf16 t[32][33];
    int b = blockIdx.z;
    const bf16* Vb = V + (size_t)b * Sc * Dc;
    bf16* Vtb = Vt + (size_t)b * Dc * Sc;
    int s0 = blockIdx.x * 32, d0 = blockIdx.y * 32;
    int tx = threadIdx.x, ty = threadIdx.y;
#pragma unroll
    for (int i = 0; i < 4; i++)
        t[ty + 8 * i][tx] = Vb[(size_t)(s0 + ty + 8 * i) * Dc + d0 + tx];
    __syncthreads();
#pragma unroll
    for (int i = 0; i < 4; i++)
        Vtb[(size_t)(d0 + ty + 8 * i) * Sc + s0 + tx] = t[tx][ty + 8 * i];
}

// ---------- GEMM: Y[M][1024] = X[M][1024] @ W + bias, X bf16, Wt[n][k] bf16 ----------
// BM=128 BN=64 BK=64, 256 threads. LDS rows are 128B -> XOR-swizzle (elem ^= (row&7)<<3)
// applied to BOTH the global_load_lds source address and the ds_read address (rule #21).
template <typename TOut>
__global__ __launch_bounds__(256) void gemm_kernel(const bf16* __restrict__ X,
                                                   const bf16* __restrict__ Wt,
                                                   const float* __restrict__ bias,
                                                   TOut* __restrict__ Y) {
    __shared__ bf16 As[128][64];  // linear dest for global_load_lds
    __shared__ bf16 Bs[64][64];
    const int mTile = blockIdx.x * 128, nTile = blockIdx.y * 64;
    const int tid = threadIdx.x;
    const int w = tid >> 6, l = tid & 63, lr = l & 15, quad = l >> 4;
    const int wm = w & 1, wn = w >> 1;
    const int srow = l >> 3;                                // 0..7 within 8-row chunk
    const int selem = ((l & 7) * 8) ^ (srow << 3);          // pre-swizzled source column

    v4f acc[4][2];
#pragma unroll
    for (int mt = 0; mt < 4; mt++)
#pragma unroll
        for (int nt = 0; nt < 2; nt++) acc[mt][nt] = v4f{0.f, 0.f, 0.f, 0.f};

    float bv[2];
#pragma unroll
    for (int nt = 0; nt < 2; nt++) bv[nt] = bias[nTile + wn * 32 + nt * 16 + lr];

    const bf16* Xbase = X + (size_t)mTile * Dc;
    const bf16* Wbase = Wt + (size_t)nTile * Dc;
    const int swzA = (lr & 7) << 3;  // read-side swizzle for this lane's rows

    for (int kt = 0; kt < Dc; kt += 64) {
        __syncthreads();
#pragma unroll
        for (int i = 0; i < 4; i++) {
            int r = w * 32 + i * 8 + srow;
            gload_lds16(Xbase + (size_t)r * Dc + kt + selem, &As[w * 32 + i * 8][0]);
        }
#pragma unroll
        for (int i = 0; i < 2; i++) {
            int r = w * 16 + i * 8 + srow;
            gload_lds16(Wbase + (size_t)r * Dc + kt + selem, &Bs[w * 16 + i * 8][0]);
        }
        __syncthreads();

        v8bf a[4][2], bb[2][2];
#pragma unroll
        for (int mt = 0; mt < 4; mt++)
#pragma unroll
            for (int kk = 0; kk < 2; kk++)
                a[mt][kk] = *(const v8bf*)&As[wm * 64 + mt * 16 + lr][(kk * 32 + quad * 8) ^ swzA];
#pragma unroll
        for (int nt = 0; nt < 2; nt++)
#pragma unroll
            for (int kk = 0; kk < 2; kk++)
                bb[nt][kk] = *(const v8bf*)&Bs[wn * 32 + nt * 16 + lr][(kk * 32 + quad * 8) ^ swzA];
#pragma unroll
        for (int kk = 0; kk < 2; kk++)
#pragma unroll
            for (int mt = 0; mt < 4; mt++)
#pragma unroll
                for (int nt = 0; nt < 2; nt++)
                    acc[mt][nt] = mfma16(a[mt][kk], bb[nt][kk], acc[mt][nt]);
    }

#pragma unroll
    for (int mt = 0; mt < 4; mt++)
#pragma unroll
        for (int nt = 0; nt < 2; nt++)
#pragma unroll
            for (int r = 0; r < 4; r++) {
                int row = mTile + wm * 64 + mt * 16 + quad * 4 + r;
                int col = nTile + wn * 32 + nt * 16 + lr;
                Y[(size_t)row * Dc + col] = (TOut)(acc[mt][nt][r] + bv[nt]);
            }
}

// ---------- fused attention: swapped QK^T, PV straight from registers, zero LDS ----------
struct KF { v8bf f0, f1, f2, f3; };
__device__ inline KF loadKF(const bf16* base, int key0, int lr, int quad) {
    KF r;
    const bf16* p0 = base + (size_t)(key0 + lr) * Dc;
    const bf16* p1 = p0 + 16 * Dc;
    r.f0 = *(const v8bf*)(p0 + quad * 8);
    r.f1 = *(const v8bf*)(p0 + 32 + quad * 8);
    r.f2 = *(const v8bf*)(p1 + quad * 8);
    r.f3 = *(const v8bf*)(p1 + 32 + quad * 8);
    return r;
}
struct VF { v4bf a0, a1, a2, a3, b0, b1, b2, b3; };  // a*: keys key0..+15, b*: key0+16..+31
__device__ inline VF loadVF(const bf16* vt, int key0, int lr, int quad) {
    VF r;
    const bf16* p = vt + key0 + quad * 4;
    r.a0 = *(const v4bf*)(p + (size_t)(0 * 16 + lr) * Sc);
    r.a1 = *(const v4bf*)(p + (size_t)(1 * 16 + lr) * Sc);
    r.a2 = *(const v4bf*)(p + (size_t)(2 * 16 + lr) * Sc);
    r.a3 = *(const v4bf*)(p + (size_t)(3 * 16 + lr) * Sc);
    r.b0 = *(const v4bf*)(p + 16 + (size_t)(0 * 16 + lr) * Sc);
    r.b1 = *(const v4bf*)(p + 16 + (size_t)(1 * 16 + lr) * Sc);
    r.b2 = *(const v4bf*)(p + 16 + (size_t)(2 * 16 + lr) * Sc);
    r.b3 = *(const v4bf*)(p + 16 + (size_t)(3 * 16 + lr) * Sc);
    return r;
}

// grid (S/64, H, B), 256 threads = 4 waves; wave w owns 16 query rows (q = r0 + lr).
__global__ __launch_bounds__(256) void attn_kernel(const bf16* __restrict__ Q,
                                                   const bf16* __restrict__ K,
                                                   const bf16* __restrict__ Vt,
                                                   float* __restrict__ attn,
                                                   bf16* __restrict__ ctx) {
    const int b = blockIdx.z, h = blockIdx.y, rb = blockIdx.x;
    const int tid = threadIdx.x, w = tid >> 6, l = tid & 63, lr = l & 15, quad = l >> 4;
    const int r0 = rb * 64 + w * 16;
    const float scale = 0.125f;  // 1/sqrt(64)
    constexpr int NG = Sc / 32;  // 64 groups of 32 keys

    const bf16* Qrow = Q + (size_t)(b * Sc + r0 + lr) * Dc + h * HDc;
    v8bf qa0 = *(const v8bf*)(Qrow + quad * 8);
    v8bf qa1 = *(const v8bf*)(Qrow + 32 + quad * 8);

    const bf16* Kbase = K + (size_t)(b * Sc) * Dc + h * HDc;
    const bf16* VtBase = Vt + (size_t)(b * Dc + h * HDc) * Sc;

    // ---- pass 1: row sums of exp(s); depth-2 register prefetch ----
    float sum = 0.f, sumB = 0.f;
    KF kA = loadKF(Kbase, 0, lr, quad);
    KF kB = loadKF(Kbase, 32, lr, quad);
    for (int g = 0; g < NG; g += 2) {
        {
            v4f s0 = v4f{0.f, 0.f, 0.f, 0.f}, s1 = v4f{0.f, 0.f, 0.f, 0.f};
            s0 = mfma16(kA.f0, qa0, s0); s0 = mfma16(kA.f1, qa1, s0);
            s1 = mfma16(kA.f2, qa0, s1); s1 = mfma16(kA.f3, qa1, s1);
            int ng = (g + 2 < NG) ? g + 2 : g;
            kA = loadKF(Kbase, ng * 32, lr, quad);
#pragma unroll
            for (int r = 0; r < 4; r++) sum += __expf(s0[r] * scale);
#pragma unroll
            for (int r = 0; r < 4; r++) sumB += __expf(s1[r] * scale);
        }
        {
            v4f s0 = v4f{0.f, 0.f, 0.f, 0.f}, s1 = v4f{0.f, 0.f, 0.f, 0.f};
            s0 = mfma16(kB.f0, qa0, s0); s0 = mfma16(kB.f1, qa1, s0);
            s1 = mfma16(kB.f2, qa0, s1); s1 = mfma16(kB.f3, qa1, s1);
            int ng = (g + 3 < NG) ? g + 3 : g + 1;
            kB = loadKF(Kbase, ng * 32, lr, quad);
#pragma unroll
            for (int r = 0; r < 4; r++) sum += __expf(s0[r] * scale);
#pragma unroll
            for (int r = 0; r < 4; r++) sumB += __expf(s1[r] * scale);
        }
    }
    sum += sumB;
    sum += __shfl_xor(sum, 16);  // reduce across quads (key partition)
    sum += __shfl_xor(sum, 32);
    const float inv = 1.0f / sum;

    float* attnRow = attn + ((size_t)((b * Hc + h) * Sc + r0 + lr)) * Sc;

    v4f acc[4];
#pragma unroll
    for (int nt = 0; nt < 4; nt++) acc[nt] = v4f{0.f, 0.f, 0.f, 0.f};

    // ---- pass 2: recompute scores, write attn, PV from registers; depth-2 prefetch ----
    KF k2A = loadKF(Kbase, 0, lr, quad);
    VF v2A = loadVF(VtBase, 0, lr, quad);
    KF k2B = loadKF(Kbase, 32, lr, quad);
    VF v2B = loadVF(VtBase, 32, lr, quad);

    for (int g = 0; g < NG; g += 2) {
        {
            v4f s0 = v4f{0.f, 0.f, 0.f, 0.f}, s1 = v4f{0.f, 0.f, 0.f, 0.f};
            s0 = mfma16(k2A.f0, qa0, s0); s0 = mfma16(k2A.f1, qa1, s0);
            s1 = mfma16(k2A.f2, qa0, s1); s1 = mfma16(k2A.f3, qa1, s1);
            int ng = (g + 2 < NG) ? g + 2 : g;
            KF nk = loadKF(Kbase, ng * 32, lr, quad);
            VF nv = loadVF(VtBase, ng * 32, lr, quad);
            v4f p0, p1;
            v4bf pb0, pb1;
#pragma unroll
            for (int r = 0; r < 4; r++) { p0[r] = __expf(s0[r] * scale) * inv; pb0[r] = (bf16)p0[r]; }
#pragma unroll
            for (int r = 0; r < 4; r++) { p1[r] = __expf(s1[r] * scale) * inv; pb1[r] = (bf16)p1[r]; }
            *(v4f*)(attnRow + g * 32 + quad * 4) = p0;
            *(v4f*)(attnRow + g * 32 + 16 + quad * 4) = p1;
            acc[0] = mfma16x16(pb0, v2A.a0, acc[0]); acc[1] = mfma16x16(pb0, v2A.a1, acc[1]);
            acc[2] = mfma16x16(pb0, v2A.a2, acc[2]); acc[3] = mfma16x16(pb0, v2A.a3, acc[3]);
            acc[0] = mfma16x16(pb1, v2A.b0, acc[0]); acc[1] = mfma16x16(pb1, v2A.b1, acc[1]);
            acc[2] = mfma16x16(pb1, v2A.b2, acc[2]); acc[3] = mfma16x16(pb1, v2A.b3, acc[3]);
            k2A = nk; v2A = nv;
        }
        {
            v4f s0 = v4f{0.f, 0.f, 0.f, 0.f}, s1 = v4f{0.f, 0.f, 0.f, 0.f};
            s0 = mfma16(k2B.f0, qa0, s0); s0 = mfma16(k2B.f1, qa1, s0);
            s1 = mfma16(k2B.f2, qa0, s1); s1 = mfma16(k2B.f3, qa1, s1);
            int ng = (g + 3 < NG) ? g + 3 : g + 1;
            KF nk = loadKF(Kbase, ng * 32, lr, quad);
            VF nv = loadVF(VtBase, ng * 32, lr, quad);
            v4f p0, p1;
            v4bf pb0, pb1;
#pragma unroll
            for (int r = 0; r < 4; r++) { p0[r] = __expf(s0[r] * scale) * inv; pb0[r] = (bf16)p0[r]; }
#pragma unroll
            for (int r = 0; r < 4; r++) { p1[r] = __expf(s1[r] * scale) * inv; pb1[r] = (bf16)p1[r]; }
            *(v4f*)(attnRow + (g + 1) * 32 + quad * 4) = p0;
            *(v4f*)(attnRow + (g + 1) * 32 + 16 + quad * 4) = p1;
            acc[0] = mfma16x16(pb0, v2B.a0, acc[0]); acc[1] = mfma16x16(pb0, v2B.a1, acc[1]);
            acc[2] = mfma16x16(pb0, v2B.a2, acc[2]); acc[3] = mfma16x16(pb0, v2B.a3, acc[3]);
            acc[0] = mfma16x16(pb1, v2B.b0, acc[0]); acc[1] = mfma16x16(pb1, v2B.b1, acc[1]);
            acc[2] = mfma16x16(pb1, v2B.b2, acc[2]); acc[3] = mfma16x16(pb1, v2B.b3, acc[3]);
            k2B = nk; v2B = nv;
        }
    }

    asm volatile("s_nop 7" :::);  // MFMA D-write -> VALU read hazard guard (asm fallback path)

#pragma unroll
    for (int nt = 0; nt < 4; nt++)
#pragma unroll
        for (int r = 0; r < 4; r++) {
            size_t row = (size_t)(b * Sc + r0 + quad * 4 + r);
            ctx[row * Dc + h * HDc + nt * 16 + lr] = (bf16)acc[nt][r];
        }
}

extern "C" void kernel_launch(void* const* d_in, const int* in_sizes, int n_in,
                              void* d_out, int out_size, void* d_ws, size_t ws_size,
                              hipStream_t stream) {
    const float* q  = (const float*)d_in[0];
    const float* k  = (const float*)d_in[1];
    const float* v  = (const float*)d_in[2];
    // d_in[3] = attn_mask: mathematically unused by the reference
    const float* Wq = (const float*)d_in[4];
    const float* bq = (const float*)d_in[5];
    const float* Wk = (const float*)d_in[6];
    const float* bk = (const float*)d_in[7];
    const float* Wv = (const float*)d_in[8];
    const float* bv = (const float*)d_in[9];
    const float* Wo = (const float*)d_in[10];
    const float* bo = (const float*)d_in[11];

    char* ws = (char*)d_ws;
    const size_t MB8 = 8388608;
    bf16* T0  = (bf16*)(ws);             // 8 MB: bf16 of current input tensor
    bf16* Qbf = (bf16*)(ws + 1 * MB8);   // 8 MB
    bf16* Kbf = (bf16*)(ws + 2 * MB8);   // 8 MB
    bf16* Vbf = (bf16*)(ws + 3 * MB8);   // 8 MB
    bf16* Vt  = (bf16*)(ws + 4 * MB8);   // 8 MB
    bf16* Wts = (bf16*)(ws + 5 * MB8);   // 8 MB: 4 x 2 MB stacked [n][k]
    bf16* Wqt = Wts;
    bf16* Wkt = Wts + 1 * (size_t)(Dc * Dc);
    bf16* Wvt = Wts + 2 * (size_t)(Dc * Dc);
    bf16* Wot = Wts + 3 * (size_t)(Dc * Dc);
    bf16* ctx = Vbf;  // reuse: Vbf dead after vtrans

    float* outp = (float*)d_out;
    float* attn = outp + (size_t)Mr * Dc;  // offset 4,194,304

    wtrans_kernel<<<dim3(32, 32, 4), dim3(32, 8), 0, stream>>>(Wq, Wk, Wv, Wo, Wts);

    cvt_kernel<<<dim3(2048), 256, 0, stream>>>(q, T0);
    gemm_kernel<bf16><<<dim3(32, 16), 256, 0, stream>>>(T0, Wqt, bq, Qbf);
    cvt_kernel<<<dim3(2048), 256, 0, stream>>>(k, T0);
    gemm_kernel<bf16><<<dim3(32, 16), 256, 0, stream>>>(T0, Wkt, bk, Kbf);
    cvt_kernel<<<dim3(2048), 256, 0, stream>>>(v, T0);
    gemm_kernel<bf16><<<dim3(32, 16), 256, 0, stream>>>(T0, Wvt, bv, Vbf);

    vtrans_kernel<<<dim3(64, 32, 2), dim3(32, 8), 0, stream>>>(Vbf, Vt);
    attn_kernel<<<dim3(32, 16, 2), 256, 0, stream>>>(Qbf, Kbf, Vt, attn, ctx);
    gemm_kernel<float><<<dim3(32, 16), 256, 0, stream>>>(ctx, Wot, bo, outp);
}

// Round 3
// 986.186 us; speedup vs baseline: 1.1184x; 1.1184x over previous
//
#include <hip/hip_runtime.h>
#include <hip/hip_bf16.h>

typedef __bf16 bf16;
typedef bf16 v8bf __attribute__((ext_vector_type(8)));
typedef bf16 v4bf __attribute__((ext_vector_type(4)));
typedef float v4f __attribute__((ext_vector_type(4)));

constexpr int Bc = 2, Sc = 2048, Dc = 1024, Hc = 16, HDc = 64;
constexpr int Mr = Bc * Sc;  // 4096 rows for projection GEMMs

__device__ inline v4f mfma16(v8bf a, v8bf b, v4f c) {
    return __builtin_amdgcn_mfma_f32_16x16x32_bf16(a, b, c, 0, 0, 0);
}

__device__ inline void gload_lds16(const void* g, void* l) {
    __builtin_amdgcn_global_load_lds((__attribute__((address_space(1))) void*)g,
                                     (__attribute__((address_space(3))) void*)l, 16, 0, 0);
}

// ---------- weight transpose+cvt: fp32 W[k][n] -> bf16 Wt[n][k], 4 matrices stacked ----------
__global__ void wtrans_kernel(const float* __restrict__ Wq, const float* __restrict__ Wk,
                              const float* __restrict__ Wv, const float* __restrict__ Wo,
                              bf16* __restrict__ out) {
    __shared__ float t[32][33];
    const float* W = (blockIdx.z == 0) ? Wq : (blockIdx.z == 1) ? Wk : (blockIdx.z == 2) ? Wv : Wo;
    bf16* Wt = out + (size_t)blockIdx.z * (Dc * Dc);
    int x0 = blockIdx.x * 32, y0 = blockIdx.y * 32;
    int tx = threadIdx.x, ty = threadIdx.y;
#pragma unroll
    for (int i = 0; i < 4; i++)
        t[ty + 8 * i][tx] = W[(size_t)(y0 + ty + 8 * i) * Dc + x0 + tx];
    __syncthreads();
#pragma unroll
    for (int i = 0; i < 4; i++)
        Wt[(size_t)(x0 + ty + 8 * i) * Dc + y0 + tx] = (bf16)t[tx][ty + 8 * i];
}

// ---------- fp32 -> bf16 convert (vectorized) ----------
__global__ void cvt_kernel(const float* __restrict__ in, bf16* __restrict__ out) {
    size_t i = ((size_t)blockIdx.x * blockDim.x + threadIdx.x) * 8;
    float4 f0 = *(const float4*)(in + i);
    float4 f1 = *(const float4*)(in + i + 4);
    v8bf v;
    v[0] = (bf16)f0.x; v[1] = (bf16)f0.y; v[2] = (bf16)f0.z; v[3] = (bf16)f0.w;
    v[4] = (bf16)f1.x; v[5] = (bf16)f1.y; v[6] = (bf16)f1.z; v[7] = (bf16)f1.w;
    *(v8bf*)(out + i) = v;
}

// ---------- V transpose (bf16): per b, [S][D] -> [D][S] ----------
__global__ void vtrans_kernel(const bf16* __restrict__ V, bf16* __restrict__ Vt) {
    __shared__ bf16 t[32][33];
    int b = blockIdx.z;
    const bf16* Vb = V + (size_t)b * Sc * Dc;
    bf16* Vtb = Vt + (size_t)b * Dc * Sc;
    int s0 = blockIdx.x * 32, d0 = blockIdx.y * 32;
    int tx = threadIdx.x, ty = threadIdx.y;
#pragma unroll
    for (int i = 0; i < 4; i++)
        t[ty + 8 * i][tx] = Vb[(size_t)(s0 + ty + 8 * i) * Dc + d0 + tx];
    __syncthreads();
#pragma unroll
    for (int i = 0; i < 4; i++)
        Vtb[(size_t)(d0 + ty + 8 * i) * Sc + s0 + tx] = t[tx][ty + 8 * i];
}

// ---------- GEMM: Y[M][1024] = X[M][1024] @ W + bias, X bf16, Wt[n][k] bf16 ----------
// BM=128 BN=64 BK=64, 256 threads. Double-buffered LDS, counted vmcnt(6) (never a full
// drain while prefetch is in flight), XOR-swizzle on BOTH gload source and ds_read.
// blockIdx.z selects among (up to) 2 stacked problems (X/Wt/Y strided, bias selected).
template <typename TOut>
__global__ __launch_bounds__(256) void gemm_kernel(const bf16* __restrict__ X0,
                                                   const bf16* __restrict__ W0,
                                                   const float* __restrict__ bias0,
                                                   const float* __restrict__ bias1,
                                                   TOut* __restrict__ Y0) {
    __shared__ bf16 As[2][128][64];
    __shared__ bf16 Bs[2][64][64];
    const int z = blockIdx.z;
    const bf16* X = X0 + (size_t)z * Mr * Dc;
    const bf16* Wt = W0 + (size_t)z * Dc * Dc;
    const float* bias = z ? bias1 : bias0;
    TOut* Y = Y0 + (size_t)z * Mr * Dc;

    const int mTile = blockIdx.x * 128, nTile = blockIdx.y * 64;
    const int tid = threadIdx.x;
    const int w = tid >> 6, l = tid & 63, lr = l & 15, quad = l >> 4;
    const int wm = w & 1, wn = w >> 1;
    const int srow = l >> 3;                        // 0..7 within 8-row chunk
    const int scol = ((l & 7) * 8) ^ (srow << 3);   // pre-swizzled source column

    v4f acc[4][2];
#pragma unroll
    for (int mt = 0; mt < 4; mt++)
#pragma unroll
        for (int nt = 0; nt < 2; nt++) acc[mt][nt] = v4f{0.f, 0.f, 0.f, 0.f};

    float bv[2];
#pragma unroll
    for (int nt = 0; nt < 2; nt++) bv[nt] = bias[nTile + wn * 32 + nt * 16 + lr];

    const bf16* Xbase = X + (size_t)mTile * Dc;
    const bf16* Wbase = Wt + (size_t)nTile * Dc;
    const int swzA = (lr & 7) << 3;  // read-side swizzle

    // stage K-step 'kt' into buffer 'buf' (6 gload_lds per thread -> 24 KB/block)
#define STAGE(buf, kt)                                                                  \
    {                                                                                   \
        _Pragma("unroll") for (int i = 0; i < 4; i++)                                   \
            gload_lds16(Xbase + (size_t)(w * 32 + i * 8 + srow) * Dc + (kt) + scol,     \
                        &As[buf][w * 32 + i * 8][0]);                                   \
        _Pragma("unroll") for (int i = 0; i < 2; i++)                                   \
            gload_lds16(Wbase + (size_t)(w * 16 + i * 8 + srow) * Dc + (kt) + scol,     \
                        &Bs[buf][w * 16 + i * 8][0]);                                   \
    }

    STAGE(0, 0);
    for (int s = 0; s < 16; s++) {
        const int cur = s & 1;
        if (s < 15) {
            STAGE(cur ^ 1, (s + 1) * 64);
            __builtin_amdgcn_sched_barrier(0);
            asm volatile("s_waitcnt vmcnt(6)" ::: "memory");  // my 'cur' loads done; next 6 in flight
        } else {
            __builtin_amdgcn_sched_barrier(0);
            asm volatile("s_waitcnt vmcnt(0)" ::: "memory");
        }
        __builtin_amdgcn_s_barrier();
        __builtin_amdgcn_sched_barrier(0);

        v8bf a[4][2], bb[2][2];
#pragma unroll
        for (int mt = 0; mt < 4; mt++)
#pragma unroll
            for (int kk = 0; kk < 2; kk++)
                a[mt][kk] =
                    *(const v8bf*)&As[cur][wm * 64 + mt * 16 + lr][(kk * 32 + quad * 8) ^ swzA];
#pragma unroll
        for (int nt = 0; nt < 2; nt++)
#pragma unroll
            for (int kk = 0; kk < 2; kk++)
                bb[nt][kk] =
                    *(const v8bf*)&Bs[cur][wn * 32 + nt * 16 + lr][(kk * 32 + quad * 8) ^ swzA];
#pragma unroll
        for (int kk = 0; kk < 2; kk++)
#pragma unroll
            for (int mt = 0; mt < 4; mt++)
#pragma unroll
                for (int nt = 0; nt < 2; nt++)
                    acc[mt][nt] = mfma16(a[mt][kk], bb[nt][kk], acc[mt][nt]);

        __builtin_amdgcn_sched_barrier(0);
        __builtin_amdgcn_s_barrier();  // reads of 'cur' done before next iter overwrites it
    }
#undef STAGE

#pragma unroll
    for (int mt = 0; mt < 4; mt++)
#pragma unroll
        for (int nt = 0; nt < 2; nt++)
#pragma unroll
            for (int r = 0; r < 4; r++) {
                int row = mTile + wm * 64 + mt * 16 + quad * 4 + r;
                int col = nTile + wn * 32 + nt * 16 + lr;
                Y[(size_t)row * Dc + col] = (TOut)(acc[mt][nt][r] + bv[nt]);
            }
}

// ---------- fused attention: swapped QK^T, 1 wave per block for load balance ----------
// grid (S/16, H, B) = 4096 blocks, 64 threads; wave owns 16 query rows (q = r0 + lr).
__global__ __launch_bounds__(64) void attn_kernel(const bf16* __restrict__ Q,
                                                  const bf16* __restrict__ K,
                                                  const bf16* __restrict__ Vt,
                                                  float* __restrict__ attn,
                                                  bf16* __restrict__ ctx) {
    __shared__ bf16 Ps[16][40];  // P tile [q=16][k=32], 80B row stride (2-way banks: free)
    const int b = blockIdx.z, h = blockIdx.y, rb = blockIdx.x;
    const int l = threadIdx.x & 63, lr = l & 15, quad = l >> 4;
    const int r0 = rb * 16;
    const float scale = 0.125f;  // 1/sqrt(64)

    const bf16* Qrow = Q + (size_t)(b * Sc + r0 + lr) * Dc + h * HDc;
    v8bf qa0 = *(const v8bf*)(Qrow + quad * 8);
    v8bf qa1 = *(const v8bf*)(Qrow + 32 + quad * 8);

    const bf16* Kbase = K + (size_t)(b * Sc) * Dc + h * HDc;

    // pass 1: row sums of exp(s). Swapped mfma(K,Q): lane owns q=lr, k=quad*4+r.
    float sum = 0.f, sumB = 0.f;
    for (int ct = 0; ct < Sc / 16; ct += 2) {
        const bf16* Kr0 = Kbase + (size_t)(ct * 16 + lr) * Dc;
        const bf16* Kr1 = Kr0 + 16 * Dc;
        v8bf k00 = *(const v8bf*)(Kr0 + quad * 8);
        v8bf k01 = *(const v8bf*)(Kr0 + 32 + quad * 8);
        v8bf k10 = *(const v8bf*)(Kr1 + quad * 8);
        v8bf k11 = *(const v8bf*)(Kr1 + 32 + quad * 8);
        v4f s0 = v4f{0.f, 0.f, 0.f, 0.f}, s1 = v4f{0.f, 0.f, 0.f, 0.f};
        s0 = mfma16(k00, qa0, s0);
        s0 = mfma16(k01, qa1, s0);
        s1 = mfma16(k10, qa0, s1);
        s1 = mfma16(k11, qa1, s1);
#pragma unroll
        for (int r = 0; r < 4; r++) sum += __expf(s0[r] * scale);
#pragma unroll
        for (int r = 0; r < 4; r++) sumB += __expf(s1[r] * scale);
    }
    sum += sumB;
    sum += __shfl_xor(sum, 16);  // reduce across quads (key partition)
    sum += __shfl_xor(sum, 32);
    const float inv = 1.0f / sum;

    float* attnRow = attn + ((size_t)((b * Hc + h) * Sc + r0 + lr)) * Sc;
    const bf16* VtBase = Vt + (size_t)(b * Dc + h * HDc) * Sc;

    v4f acc[4];
#pragma unroll
    for (int nt = 0; nt < 4; nt++) acc[nt] = v4f{0.f, 0.f, 0.f, 0.f};

    constexpr int NT = Sc / 32;  // 64 iterations over 32-key groups
    // prologue: load K/V fragments for ctp = 0
    v8bf k00, k01, k10, k11, vb[4];
    {
        const bf16* Kr0 = Kbase + (size_t)lr * Dc;
        const bf16* Kr1 = Kr0 + 16 * Dc;
        k00 = *(const v8bf*)(Kr0 + quad * 8);
        k01 = *(const v8bf*)(Kr0 + 32 + quad * 8);
        k10 = *(const v8bf*)(Kr1 + quad * 8);
        k11 = *(const v8bf*)(Kr1 + 32 + quad * 8);
#pragma unroll
        for (int nt = 0; nt < 4; nt++)
            vb[nt] = *(const v8bf*)(VtBase + (size_t)(nt * 16 + lr) * Sc + quad * 8);
    }

    for (int ctp = 0; ctp < NT; ctp++) {
        v4f s0 = v4f{0.f, 0.f, 0.f, 0.f}, s1 = v4f{0.f, 0.f, 0.f, 0.f};
        s0 = mfma16(k00, qa0, s0);
        s0 = mfma16(k01, qa1, s0);
        s1 = mfma16(k10, qa0, s1);
        s1 = mfma16(k11, qa1, s1);

        // prefetch next iteration's K and Vt fragments (hidden under exp + PV)
        const int nc = (ctp + 1 < NT) ? ctp + 1 : ctp;
        const bf16* Kr0n = Kbase + (size_t)(nc * 32 + lr) * Dc;
        const bf16* Kr1n = Kr0n + 16 * Dc;
        v8bf n00 = *(const v8bf*)(Kr0n + quad * 8);
        v8bf n01 = *(const v8bf*)(Kr0n + 32 + quad * 8);
        v8bf n10 = *(const v8bf*)(Kr1n + quad * 8);
        v8bf n11 = *(const v8bf*)(Kr1n + 32 + quad * 8);
        v8bf vn[4];
#pragma unroll
        for (int nt = 0; nt < 4; nt++)
            vn[nt] = *(const v8bf*)(VtBase + (size_t)(nt * 16 + lr) * Sc + nc * 32 + quad * 8);

        // softmax values: lane owns q=lr, k = ctp*32 + quad*4 + r (+16 for tile1)
        v4f p0, p1;
        v4bf pb0, pb1;
#pragma unroll
        for (int r = 0; r < 4; r++) { p0[r] = __expf(s0[r] * scale) * inv; pb0[r] = (bf16)p0[r]; }
#pragma unroll
        for (int r = 0; r < 4; r++) { p1[r] = __expf(s1[r] * scale) * inv; pb1[r] = (bf16)p1[r]; }
        // float4 stores: 4 consecutive columns per lane
        *(v4f*)(attnRow + ctp * 32 + quad * 4) = p0;
        *(v4f*)(attnRow + ctp * 32 + 16 + quad * 4) = p1;
        // stash bf16 P in LDS in A-operand row-major layout
        *(v4bf*)&Ps[lr][quad * 4] = pb0;
        *(v4bf*)&Ps[lr][16 + quad * 4] = pb1;
        asm volatile("s_waitcnt lgkmcnt(0)" ::: "memory");  // wave-local: DS in-order per wave
        __builtin_amdgcn_sched_barrier(0);
        v8bf pa = *(const v8bf*)&Ps[lr][quad * 8];
#pragma unroll
        for (int nt = 0; nt < 4; nt++) acc[nt] = mfma16(pa, vb[nt], acc[nt]);

        k00 = n00; k01 = n01; k10 = n10; k11 = n11;
#pragma unroll
        for (int nt = 0; nt < 4; nt++) vb[nt] = vn[nt];
    }

#pragma unroll
    for (int nt = 0; nt < 4; nt++)
#pragma unroll
        for (int r = 0; r < 4; r++) {
            size_t row = (size_t)(b * Sc + r0 + quad * 4 + r);
            ctx[row * Dc + h * HDc + nt * 16 + lr] = (bf16)acc[nt][r];
        }
}

extern "C" void kernel_launch(void* const* d_in, const int* in_sizes, int n_in,
                              void* d_out, int out_size, void* d_ws, size_t ws_size,
                              hipStream_t stream) {
    const float* q  = (const float*)d_in[0];
    const float* k  = (const float*)d_in[1];
    const float* v  = (const float*)d_in[2];
    // d_in[3] = attn_mask: mathematically unused by the reference
    const float* Wq = (const float*)d_in[4];
    const float* bq = (const float*)d_in[5];
    const float* Wk = (const float*)d_in[6];
    const float* bk = (const float*)d_in[7];
    const float* Wv = (const float*)d_in[8];
    const float* bv = (const float*)d_in[9];
    const float* Wo = (const float*)d_in[10];
    const float* bo = (const float*)d_in[11];

    char* ws = (char*)d_ws;
    const size_t MB8 = 8388608;
    // 6 slots x 8 MB = 48 MB, aggressively reused:
    bf16* slotA = (bf16*)(ws + 0 * MB8);  // q_bf16 -> v_bf16 -> ctx
    bf16* slotB = (bf16*)(ws + 1 * MB8);  // k_bf16 -> Vt
    bf16* Wts   = (bf16*)(ws + 2 * MB8);  // 4 x 2 MB stacked [n][k] (persists)
    bf16* Qbf   = (bf16*)(ws + 3 * MB8);
    bf16* Kbf   = (bf16*)(ws + 4 * MB8);
    bf16* Vbf   = (bf16*)(ws + 5 * MB8);
    bf16* Wvt = Wts + 2 * (size_t)(Dc * Dc);
    bf16* Wot = Wts + 3 * (size_t)(Dc * Dc);

    float* outp = (float*)d_out;
    float* attn = outp + (size_t)Mr * Dc;  // offset 4,194,304

    wtrans_kernel<<<dim3(32, 32, 4), dim3(32, 8), 0, stream>>>(Wq, Wk, Wv, Wo, Wts);

    cvt_kernel<<<dim3(2048), 256, 0, stream>>>(q, slotA);
    cvt_kernel<<<dim3(2048), 256, 0, stream>>>(k, slotB);
    // fused Q+K projection: z=0 reads slotA/Wts[0]/bq -> Qbf; z=1 reads slotB/Wts[1]/bk -> Kbf
    gemm_kernel<bf16><<<dim3(32, 16, 2), 256, 0, stream>>>(slotA, Wts, bq, bk, Qbf);

    cvt_kernel<<<dim3(2048), 256, 0, stream>>>(v, slotA);
    gemm_kernel<bf16><<<dim3(32, 16, 1), 256, 0, stream>>>(slotA, Wvt, bv, bv, Vbf);

    vtrans_kernel<<<dim3(64, 32, 2), dim3(32, 8), 0, stream>>>(Vbf, slotB);  // Vt = slotB
    attn_kernel<<<dim3(128, 16, 2), 64, 0, stream>>>(Qbf, Kbf, slotB, attn, slotA);  // ctx = slotA
    gemm_kernel<float><<<dim3(32, 16, 1), 256, 0, stream>>>(slotA, Wot, bo, bo, outp);
}